// Round 7
// baseline (403.938 us; speedup 1.0000x reference)
//
#include <hip/hip_runtime.h>
#include <stdint.h>
#include <math.h>

#define N_ 4096
#define D_ 512
#define C_ 128
#define MAXC 256

typedef __attribute__((ext_vector_type(8))) short bf16x8;
typedef __attribute__((ext_vector_type(4))) float f32x4;

// ---------------- Threefry-2x32-20 (JAX-compatible) ----------------
__host__ __device__ __forceinline__ uint32_t rotl32_(uint32_t x, int d) {
  return (x << d) | (x >> (32 - d));
}
__host__ __device__ inline void tf2x32(uint32_t k0, uint32_t k1,
                                       uint32_t x0, uint32_t x1,
                                       uint32_t& y0, uint32_t& y1) {
  const uint32_t k2 = k0 ^ k1 ^ 0x1BD11BDAu;
#define TF_R(rr) { x0 += x1; x1 = rotl32_(x1, rr); x1 ^= x0; }
  x0 += k0; x1 += k1;
  TF_R(13) TF_R(15) TF_R(26) TF_R(6)
  x0 += k1; x1 += k2 + 1u;
  TF_R(17) TF_R(29) TF_R(16) TF_R(24)
  x0 += k2; x1 += k0 + 2u;
  TF_R(13) TF_R(15) TF_R(26) TF_R(6)
  x0 += k0; x1 += k1 + 3u;
  TF_R(17) TF_R(29) TF_R(16) TF_R(24)
  x0 += k1; x1 += k2 + 4u;
  TF_R(13) TF_R(15) TF_R(26) TF_R(6)
  x0 += k2; x1 += k0 + 5u;
#undef TF_R
  y0 = x0; y1 = x1;
}

__device__ __forceinline__ float gumbel_ij(uint32_t k0, uint32_t k1, uint32_t m) {
  uint32_t y0, y1;
  tf2x32(k0, k1, 0u, m, y0, y1);
  uint32_t bits = y0 ^ y1;
  uint32_t vb = (bits >> 9) | 0x3f800000u;
  float f = __uint_as_float(vb) - 1.0f;
  float u = (f == 0.0f) ? 1.1754943508222875e-38f : f;
  return -logf(-logf(u));
}

// bf16 helpers (manual RNE; no NaN inputs here)
__device__ __forceinline__ unsigned short f2bf(float x) {
  unsigned int b = __float_as_uint(x);
  b += 0x7fffu + ((b >> 16) & 1u);
  return (unsigned short)(b >> 16);
}
__device__ __forceinline__ float bf2f(unsigned short u) {
  return __uint_as_float(((unsigned int)u) << 16);
}

__device__ __forceinline__ void gll16(const void* g, void* lds) {
  __builtin_amdgcn_global_load_lds(
      (const __attribute__((address_space(1))) unsigned int*)g,
      (__attribute__((address_space(3))) unsigned int*)lds, 16, 0, 0);
}

// ---------------- Kernel Z: zero accumulators + class counters ----------------
__global__ void zero_k(float* __restrict__ accum, int* __restrict__ ccnt) {
  int t = threadIdx.x;
  if (t == 0) {
    accum[0] = 0.0f;
    ((unsigned*)accum)[1] = 0u;
    ((unsigned*)accum)[2] = 0u;
  }
  if (t < C_) ccnt[t] = 0;
}

// ---------------- Kernel A: row norms + pred argmax + bf16 split + class lists ----------------
__global__ __launch_bounds__(64) void prep_k(const float* __restrict__ inputs,
                                             const float* __restrict__ pred,
                                             const int* __restrict__ targets,
                                             float* __restrict__ sq,
                                             int* __restrict__ pam,
                                             int* __restrict__ ccnt,
                                             int* __restrict__ clist,
                                             unsigned short* __restrict__ XH,
                                             unsigned short* __restrict__ XL,
                                             int do_split, int do_list) {
  int i = blockIdx.x;
  int lane = threadIdx.x;
  const float4* rp = (const float4*)(inputs + (size_t)i * D_);
  float s = 0.0f;
#pragma unroll
  for (int q = 0; q < 2; ++q) {
    float4 v = rp[lane + 64 * q];
    s += v.x * v.x + v.y * v.y + v.z * v.z + v.w * v.w;
    if (do_split) {
      unsigned short h0 = f2bf(v.x), h1 = f2bf(v.y), h2 = f2bf(v.z), h3 = f2bf(v.w);
      unsigned short g0 = f2bf(v.x - bf2f(h0)), g1 = f2bf(v.y - bf2f(h1));
      unsigned short g2 = f2bf(v.z - bf2f(h2)), g3 = f2bf(v.w - bf2f(h3));
      uint2 hp, lp;
      hp.x = (unsigned)h0 | ((unsigned)h1 << 16); hp.y = (unsigned)h2 | ((unsigned)h3 << 16);
      lp.x = (unsigned)g0 | ((unsigned)g1 << 16); lp.y = (unsigned)g2 | ((unsigned)g3 << 16);
      *(uint2*)&XH[(size_t)i * D_ + 4 * (lane + 64 * q)] = hp;
      *(uint2*)&XL[(size_t)i * D_ + 4 * (lane + 64 * q)] = lp;
    }
  }
#pragma unroll
  for (int off = 32; off; off >>= 1) s += __shfl_down(s, off);
  if (lane == 0) sq[i] = s;

  float v0 = pred[(size_t)i * C_ + lane];
  float v1 = pred[(size_t)i * C_ + 64 + lane];
  float bv; int bi;
  if (v1 > v0) { bv = v1; bi = lane + 64; } else { bv = v0; bi = lane; }
#pragma unroll
  for (int off = 32; off; off >>= 1) {
    float ov = __shfl_down(bv, off);
    int oi = __shfl_down(bi, off);
    if (ov > bv || (ov == bv && oi < bi)) { bv = ov; bi = oi; }
  }
  if (lane == 0) {
    pam[i] = bi;
    if (do_list) {
      int t = targets[i];
      int p = atomicAdd(&ccnt[t], 1);
      if (p < MAXC) clist[t * MAXC + p] = i;
    }
  }
}

// ---------------- Kernel B v3: barrier-free MFMA K-loop (direct frag loads) ----------------
// grid 512 = 64 row-blocks x 8 col-slices; block 256 = 4 waves.
// Block tile 64 rows x 512 cols; wave w owns cols [w*128, w*128+128).
__global__ __launch_bounds__(256, 2) void bigk3_k(const unsigned short* __restrict__ XH,
                                                  const unsigned short* __restrict__ XL,
                                                  const int* __restrict__ targets,
                                                  const float* __restrict__ sq,
                                                  float* __restrict__ pD,
                                                  int* __restrict__ pI) {
  __shared__ float U[8448];       // Dl[64][132]; later aliased: MD[3072] | MI[3072]
  __shared__ float sqc[512];
  __shared__ int tcs[512];
  __shared__ float sqr[64];
  __shared__ int trs[64];

  const int tid = threadIdx.x, w = tid >> 6, l = tid & 63;
  const int rb = blockIdx.x >> 3, sl = blockIdx.x & 7;
  const int rbase = rb * 64, cbase0 = sl * 512;

  sqc[tid] = sq[cbase0 + tid]; sqc[tid + 256] = sq[cbase0 + 256 + tid];
  tcs[tid] = targets[cbase0 + tid]; tcs[tid + 256] = targets[cbase0 + 256 + tid];
  if (tid < 64) { sqr[tid] = sq[rbase + tid]; trs[tid] = targets[rbase + tid]; }

  const int lr = l & 15, lk = (l >> 4) * 8;
  // per-lane fragment base pointers (identical addresses to v2's LDS-staged data)
  const unsigned short* aH[4]; const unsigned short* aL[4];
  const unsigned short* bH[8]; const unsigned short* bL[8];
#pragma unroll
  for (int rt = 0; rt < 4; ++rt) {
    size_t o = (size_t)(rbase + rt * 16 + lr) * D_ + lk;
    aH[rt] = XH + o; aL[rt] = XL + o;
  }
#pragma unroll
  for (int c = 0; c < 8; ++c) {
    size_t o = (size_t)(cbase0 + (w * 8 + c) * 16 + lr) * D_ + lk;
    bH[c] = XH + o; bL[c] = XL + o;
  }

  f32x4 acc[4][8];
#pragma unroll
  for (int rt = 0; rt < 4; ++rt)
#pragma unroll
    for (int c = 0; c < 8; ++c) acc[rt][c] = (f32x4){0.f, 0.f, 0.f, 0.f};

  // Barrier-free K-loop: compiler pipelines next-kc loads under MFMA via counted vmcnt.
  for (int kc = 0; kc < 16; ++kc) {
    const int kb = kc * 32;
    bf16x8 ah[4], al_[4];
#pragma unroll
    for (int rt = 0; rt < 4; ++rt) {
      ah[rt] = *(const bf16x8*)(aH[rt] + kb);
      al_[rt] = *(const bf16x8*)(aL[rt] + kb);
    }
#pragma unroll
    for (int c = 0; c < 8; ++c) {
      bf16x8 bh = *(const bf16x8*)(bH[c] + kb);
      bf16x8 bl = *(const bf16x8*)(bL[c] + kb);
#pragma unroll
      for (int rt = 0; rt < 4; ++rt) {
        acc[rt][c] = __builtin_amdgcn_mfma_f32_16x16x32_bf16(ah[rt], bh, acc[rt][c], 0, 0, 0);
        acc[rt][c] = __builtin_amdgcn_mfma_f32_16x16x32_bf16(ah[rt], bl, acc[rt][c], 0, 0, 0);
        acc[rt][c] = __builtin_amdgcn_mfma_f32_16x16x32_bf16(al_[rt], bh, acc[rt][c], 0, 0, 0);
      }
    }
  }

  // ---- dist + per-thread top-12 scan, 4 phases ----
  float* Dl = U;                       // [64][132]
  float dl[12]; int il[12];
#pragma unroll
  for (int q = 0; q < 12; ++q) { dl[q] = INFINITY; il[q] = 0; }
  const int srow = tid >> 2, scq = tid & 3;
  const int orow = (l >> 4) * 4;

  for (int g = 0; g < 4; ++g) {
    __syncthreads();                   // sqc/tcs visible (g=0); prev scan done (g>0)
    if (w == g) {
#pragma unroll
      for (int rt = 0; rt < 4; ++rt)
#pragma unroll
        for (int c = 0; c < 8; ++c)
#pragma unroll
          for (int r = 0; r < 4; ++r) {
            int row = rt * 16 + orow + r;
            int cl = c * 16 + lr;
            float d2 = sqr[row] + sqc[g * 128 + cl] - 2.0f * acc[rt][c][r];
            float d = (trs[row] == tcs[g * 128 + cl]) ? INFINITY : sqrtf(fmaxf(d2, 1e-12f));
            Dl[row * 132 + cl] = d;
          }
    }
    __syncthreads();
    for (int q = 0; q < 32; ++q) {
      float d = Dl[srow * 132 + scq + 4 * q];
      if (d < dl[11]) {
        int col = cbase0 + g * 128 + scq + 4 * q;
        bool placed = false;
#pragma unroll
        for (int t = 11; t >= 1; --t) {
          if (!placed) {
            if (dl[t - 1] > d) { dl[t] = dl[t - 1]; il[t] = il[t - 1]; }
            else { dl[t] = d; il[t] = col; placed = true; }
          }
        }
        if (!placed) { dl[0] = d; il[0] = col; }
      }
    }
  }

  // merge 4 per-thread lists per row -> per-(row,slice) top-12 (MD/MI alias Dl)
  __syncthreads();                     // all scans done before overwriting Dl region
  float* MD = U;                       // [256][12]
  int* MI = (int*)(U + 3072);          // [256][12]
#pragma unroll
  for (int q = 0; q < 12; ++q) { MD[tid * 12 + q] = dl[q]; MI[tid * 12 + q] = il[q]; }
  __syncthreads();
  if ((tid & 3) == 0) {
    int row = tid >> 2;
    int grow = rbase + row;
    float* outD = pD + ((size_t)grow * 8 + sl) * 12;
    int* outI = pI + ((size_t)grow * 8 + sl) * 12;
    int p0 = 0, p1 = 0, p2 = 0, p3 = 0;
    for (int o = 0; o < 12; ++o) {
      float bd = INFINITY; int bi = 0x7fffffff; int bc = 0;
      if (p0 < 12) { float d = MD[(row * 4 + 0) * 12 + p0]; int ix = MI[(row * 4 + 0) * 12 + p0]; if (d < bd || (d == bd && ix < bi)) { bd = d; bi = ix; bc = 0; } }
      if (p1 < 12) { float d = MD[(row * 4 + 1) * 12 + p1]; int ix = MI[(row * 4 + 1) * 12 + p1]; if (d < bd || (d == bd && ix < bi)) { bd = d; bi = ix; bc = 1; } }
      if (p2 < 12) { float d = MD[(row * 4 + 2) * 12 + p2]; int ix = MI[(row * 4 + 2) * 12 + p2]; if (d < bd || (d == bd && ix < bi)) { bd = d; bi = ix; bc = 2; } }
      if (p3 < 12) { float d = MD[(row * 4 + 3) * 12 + p3]; int ix = MI[(row * 4 + 3) * 12 + p3]; if (d < bd || (d == bd && ix < bi)) { bd = d; bi = ix; bc = 3; } }
      outD[o] = bd; outI[o] = bi;
      if (bc == 0) p0++; else if (bc == 1) p1++; else if (bc == 2) p2++; else p3++;
    }
  }
}

// ---------------- Kernel B v1 (fp32 fallback when ws too small) ----------------
__global__ __launch_bounds__(256, 2) void bigk_k(const float* __restrict__ inputs,
                                                 const int* __restrict__ targets,
                                                 const float* __restrict__ sq,
                                                 float* __restrict__ pD,
                                                 int* __restrict__ pI) {
  __shared__ float U[10496];
  __shared__ float sqc[256];
  __shared__ int tcs[256];
  __shared__ float sqr[64];
  __shared__ int trs[64];

  float* Al = U;
  float* Bl = U + 2176;
  float* Dl = U;
  float* MD = U;
  int* MI = (int*)(U + 3072);

  const int tid = threadIdx.x;
  const int rb = blockIdx.x >> 3, sl = blockIdx.x & 7;
  const int rbase = rb * 64, cbase0 = sl * 512;

  if (tid < 64) { sqr[tid] = sq[rbase + tid]; trs[tid] = targets[rbase + tid]; }

  float dl[12]; int il[12];
#pragma unroll
  for (int q = 0; q < 12; ++q) { dl[q] = INFINITY; il[q] = 0; }

  const int w = tid >> 6, lane = tid & 63;
  const int rg = lane >> 3, cg = lane & 7;
  const int r0 = rg * 8, c0l = w * 64 + cg * 8;
  const int srow = tid >> 2, scq = tid & 3;

  for (int ci = 0; ci < 2; ++ci) {
    const int cbase = cbase0 + ci * 256;
    __syncthreads();
    sqc[tid] = sq[cbase + tid];
    tcs[tid] = targets[cbase + tid];

    float acc[8][8];
#pragma unroll
    for (int a = 0; a < 8; ++a)
#pragma unroll
      for (int b = 0; b < 8; ++b) acc[a][b] = 0.0f;

    for (int kc = 0; kc < 16; ++kc) {
      const int kb = kc * 32;
      __syncthreads();
#pragma unroll
      for (int q = 0; q < 2; ++q) {
        int idx = tid + 256 * q;
        int row = idx >> 3, kq = idx & 7;
        float4 v = *(const float4*)(inputs + (size_t)(rbase + row) * D_ + kb + kq * 4);
        Al[(4 * kq + 0) * 68 + row] = v.x;
        Al[(4 * kq + 1) * 68 + row] = v.y;
        Al[(4 * kq + 2) * 68 + row] = v.z;
        Al[(4 * kq + 3) * 68 + row] = v.w;
      }
#pragma unroll
      for (int q = 0; q < 8; ++q) {
        int idx = tid + 256 * q;
        int col = idx >> 3, kq = idx & 7;
        float4 v = *(const float4*)(inputs + (size_t)(cbase + col) * D_ + kb + kq * 4);
        Bl[(4 * kq + 0) * 260 + col] = v.x;
        Bl[(4 * kq + 1) * 260 + col] = v.y;
        Bl[(4 * kq + 2) * 260 + col] = v.z;
        Bl[(4 * kq + 3) * 260 + col] = v.w;
      }
      __syncthreads();
#pragma unroll 4
      for (int k = 0; k < 32; ++k) {
        float4 a0 = *(const float4*)&Al[k * 68 + r0];
        float4 a1 = *(const float4*)&Al[k * 68 + r0 + 4];
        float4 b0 = *(const float4*)&Bl[k * 260 + c0l];
        float4 b1 = *(const float4*)&Bl[k * 260 + c0l + 4];
        float a_[8] = {a0.x, a0.y, a0.z, a0.w, a1.x, a1.y, a1.z, a1.w};
        float b_[8] = {b0.x, b0.y, b0.z, b0.w, b1.x, b1.y, b1.z, b1.w};
#pragma unroll
        for (int ii = 0; ii < 8; ++ii)
#pragma unroll
          for (int jj = 0; jj < 8; ++jj)
            acc[ii][jj] = fmaf(a_[ii], b_[jj], acc[ii][jj]);
      }
    }

    for (int h = 0; h < 2; ++h) {
      __syncthreads();
#pragma unroll
      for (int i = 0; i < 8; ++i) {
        float si = sqr[r0 + i];
        int ti_ = trs[r0 + i];
#pragma unroll
        for (int jj = 0; jj < 4; ++jj) {
          int j = 4 * h + jj;
          float d2 = si + sqc[c0l + j] - 2.0f * acc[i][j];
          float d = (ti_ == tcs[c0l + j]) ? INFINITY : sqrtf(fmaxf(d2, 1e-12f));
          Dl[(r0 + i) * 129 + (w * 32 + cg * 4 + jj)] = d;
        }
      }
      __syncthreads();
      for (int q = 0; q < 32; ++q) {
        float d = Dl[srow * 129 + scq * 32 + q];
        if (d < dl[11]) {
          int u = scq * 32 + q;
          int col = cbase + ((u >> 5) << 6) + (((u >> 2) & 7) << 3) + (h << 2) + (u & 3);
          bool placed = false;
#pragma unroll
          for (int t = 11; t >= 1; --t) {
            if (!placed) {
              if (dl[t - 1] > d) { dl[t] = dl[t - 1]; il[t] = il[t - 1]; }
              else { dl[t] = d; il[t] = col; placed = true; }
            }
          }
          if (!placed) { dl[0] = d; il[0] = col; }
        }
      }
    }
  }

  __syncthreads();
#pragma unroll
  for (int q = 0; q < 12; ++q) { MD[tid * 12 + q] = dl[q]; MI[tid * 12 + q] = il[q]; }
  __syncthreads();
  if ((tid & 3) == 0) {
    int row = tid >> 2;
    int grow = rbase + row;
    float* outD = pD + ((size_t)grow * 8 + sl) * 12;
    int* outI = pI + ((size_t)grow * 8 + sl) * 12;
    int p0 = 0, p1 = 0, p2 = 0, p3 = 0;
    for (int o = 0; o < 12; ++o) {
      float bd = INFINITY; int bi = 0x7fffffff; int bc = 0;
      if (p0 < 12) { float d = MD[(row * 4 + 0) * 12 + p0]; int ix = MI[(row * 4 + 0) * 12 + p0]; if (d < bd || (d == bd && ix < bi)) { bd = d; bi = ix; bc = 0; } }
      if (p1 < 12) { float d = MD[(row * 4 + 1) * 12 + p1]; int ix = MI[(row * 4 + 1) * 12 + p1]; if (d < bd || (d == bd && ix < bi)) { bd = d; bi = ix; bc = 1; } }
      if (p2 < 12) { float d = MD[(row * 4 + 2) * 12 + p2]; int ix = MI[(row * 4 + 2) * 12 + p2]; if (d < bd || (d == bd && ix < bi)) { bd = d; bi = ix; bc = 2; } }
      if (p3 < 12) { float d = MD[(row * 4 + 3) * 12 + p3]; int ix = MI[(row * 4 + 3) * 12 + p3]; if (d < bd || (d == bd && ix < bi)) { bd = d; bi = ix; bc = 3; } }
      outD[o] = bd; outI[o] = bi;
      if (bc == 0) p0++; else if (bc == 1) p1++; else if (bc == 2) p2++; else p3++;
    }
  }
}

// ---------------- Kernel C: per-row finalize (exact recompute of top-12) ----------------
__device__ __forceinline__ float wdist2(float4 xi0, float4 xi1,
                                        const float* __restrict__ inputs,
                                        const float* __restrict__ sq,
                                        int i, int j, int lane) {
  const float4* b = (const float4*)(inputs + (size_t)j * D_);
  float4 y0 = b[lane], y1 = b[lane + 64];
  float s = xi0.x * y0.x + xi0.y * y0.y + xi0.z * y0.z + xi0.w * y0.w +
            xi1.x * y1.x + xi1.y * y1.y + xi1.z * y1.z + xi1.w * y1.w;
#pragma unroll
  for (int off = 32; off; off >>= 1) s += __shfl_xor(s, off);
  float d2 = sq[i] + sq[j] - 2.0f * s;
  return sqrtf(fmaxf(d2, 1e-12f));
}

__global__ __launch_bounds__(256) void finalize_k(const float* __restrict__ inputs,
                                                  const int* __restrict__ targets,
                                                  const float* __restrict__ prob,
                                                  const float* __restrict__ thr_p,
                                                  const float* __restrict__ sq,
                                                  const int* __restrict__ pam,
                                                  const float* __restrict__ pD,
                                                  const int* __restrict__ pI,
                                                  const int* __restrict__ ccnt,
                                                  const int* __restrict__ clist,
                                                  float* __restrict__ accum,
                                                  uint32_t kp0, uint32_t kp1,
                                                  uint32_t kq0, uint32_t kq1,
                                                  int use_list) {
  const int wid = threadIdx.x >> 6, lane = threadIdx.x & 63;
  const int i = blockIdx.x * 4 + wid;
  const float thr = *thr_p;
  const int ti = targets[i];

  // gumbel argmax over same-class columns (both keys)
  float g1 = -INFINITY; int i1 = 0;
  float g2 = -INFINITY; int i2 = 0;
  int f2 = 0;
  if (use_list) {
    int cnt = ccnt[ti]; if (cnt > MAXC) cnt = MAXC;
    const int* lst = clist + (size_t)ti * MAXC;
    for (int base = 0; base < cnt; base += 64) {
      int idx = base + lane;
      if (idx < cnt) {
        int j = lst[idx];
        if (j != i) {
          uint32_t m = ((uint32_t)i << 12) | (uint32_t)j;
          float g = gumbel_ij(kp0, kp1, m);
          if (g > g1 || (g == g1 && j < i1)) { g1 = g; i1 = j; }
          if (prob[j] >= thr) {
            float gg = gumbel_ij(kq0, kq1, m);
            if (gg > g2 || (gg == g2 && j < i2)) { g2 = gg; i2 = j; }
            f2 = 1;
          }
        }
      }
    }
  } else {
    for (int j = lane; j < N_; j += 64) {
      if (targets[j] == ti && j != i) {
        uint32_t m = ((uint32_t)i << 12) | (uint32_t)j;
        float g = gumbel_ij(kp0, kp1, m);
        if (g > g1 || (g == g1 && j < i1)) { g1 = g; i1 = j; }
        if (prob[j] >= thr) {
          float gg = gumbel_ij(kq0, kq1, m);
          if (gg > g2 || (gg == g2 && j < i2)) { g2 = gg; i2 = j; }
          f2 = 1;
        }
      }
    }
  }
#pragma unroll
  for (int off = 32; off; off >>= 1) {
    float og = __shfl_xor(g1, off); int oi = __shfl_xor(i1, off);
    if (og > g1 || (og == g1 && oi < i1)) { g1 = og; i1 = oi; }
    float oh = __shfl_xor(g2, off); int oj = __shfl_xor(i2, off);
    if (oh > g2 || (oh == g2 && oj < i2)) { g2 = oh; i2 = oj; }
  }
  f2 = __any(f2);
  const int ap_idx = i1;
  const int new_pos = f2 ? i2 : ap_idx;

  const float4* arow = (const float4*)(inputs + (size_t)i * D_);
  float4 xi0 = arow[lane], xi1 = arow[lane + 64];
  const float ap0 = wdist2(xi0, xi1, inputs, sq, i, ap_idx, lane);
  const float ap_new = wdist2(xi0, xi1, inputs, sq, i, new_pos, lane);

  // merge 8 slice lists -> 12 candidate indices
  const float* rowD = pD + (size_t)i * 96;
  const int* rowI = pI + (size_t)i * 96;
  int ci_[12];
  {
    int p0 = 0, p1 = 0, p2 = 0, p3 = 0, p4 = 0, p5 = 0, p6 = 0, p7 = 0;
#pragma unroll
    for (int o = 0; o < 12; ++o) {
      float bd = INFINITY; int bi = 0x7fffffff; int bs = 0;
#define HEADQ(s, ps) if (ps < 12) { float d = rowD[(s) * 12 + ps]; int ix = rowI[(s) * 12 + ps]; if (d < bd || (d == bd && ix < bi)) { bd = d; bi = ix; bs = (s); } }
      HEADQ(0, p0) HEADQ(1, p1) HEADQ(2, p2) HEADQ(3, p3)
      HEADQ(4, p4) HEADQ(5, p5) HEADQ(6, p6) HEADQ(7, p7)
#undef HEADQ
      ci_[o] = bi;
      if (bs == 0) p0++; else if (bs == 1) p1++; else if (bs == 2) p2++; else if (bs == 3) p3++;
      else if (bs == 4) p4++; else if (bs == 5) p5++; else if (bs == 6) p6++; else p7++;
    }
  }
  // exact fp32 recompute of the 12 candidate distances
  float de[12];
#pragma unroll
  for (int o = 0; o < 12; ++o) de[o] = wdist2(xi0, xi1, inputs, sq, i, ci_[o], lane);

  // rank-0: min by (d, idx)
  float an0 = de[0]; int an_idx = ci_[0]; int minpos = 0;
#pragma unroll
  for (int o = 1; o < 12; ++o)
    if (de[o] < an0 || (de[o] == an0 && ci_[o] < an_idx)) { an0 = de[o]; an_idx = ci_[o]; minpos = o; }
  // an_B: first confident among ranks 1..11
  float anB = INFINITY; int anBi = 0x7fffffff; bool fB = false;
#pragma unroll
  for (int o = 0; o < 12; ++o) {
    if (o != minpos) {
      bool cf = prob[ci_[o]] >= thr;
      if (cf && (de[o] < anB || (de[o] == anB && ci_[o] < anBi))) { anB = de[o]; anBi = ci_[o]; fB = true; }
    }
  }
  if (!fB) {  // r = TOPK-1: the largest of the 12
    anB = de[0]; anBi = ci_[0];
#pragma unroll
    for (int o = 1; o < 12; ++o)
      if (de[o] > anB || (de[o] == anB && ci_[o] > anBi)) { anB = de[o]; anBi = ci_[o]; }
  }
  const float an_B = anB;

  if (lane == 0) {
    bool neg_conf = prob[an_idx] >= thr;
    bool pos_conf = prob[ap_idx] >= thr;
    bool is_fn = (pam[an_idx] == ti);
    bool caseB = pos_conf && !neg_conf && is_fn;
    bool swap_ = !pos_conf && (neg_conf || !is_fn);
    bool inverse = !pos_conf && !neg_conf && is_fn;
    float half = 0.5f * (ap0 + an0);
    float ap = caseB ? half : (swap_ ? ap_new : ap0);
    float an = caseB ? an_B : (swap_ ? half : an0);
    const float margin = 0.3f;
    float rl = inverse ? fmaxf(an - ap + margin, 0.0f) : fmaxf(ap - an + margin, 0.0f);
    bool conf_i = prob[i] >= thr;
    if (conf_i) {
      atomicAdd(&accum[0], rl);
      atomicAdd(((unsigned*)accum) + 2, 1u);
      if (an >= ap) atomicAdd(((unsigned*)accum) + 1, 1u);
    }
  }
}

__global__ void writeout_k(const float* __restrict__ accum, float* __restrict__ out) {
  unsigned correct = ((const unsigned*)accum)[1];
  unsigned cnt = ((const unsigned*)accum)[2];
  out[0] = accum[0] / fmaxf((float)cnt, 1.0f);
  out[1] = (float)correct;
}

extern "C" void kernel_launch(void* const* d_in, const int* in_sizes, int n_in,
                              void* d_out, int out_size, void* d_ws, size_t ws_size,
                              hipStream_t stream) {
  const float* inputs = (const float*)d_in[0];
  const float* pred = (const float*)d_in[1];
  const int* targets = (const int*)d_in[2];
  const float* prob = (const float*)d_in[4];
  const float* thr = (const float*)d_in[5];
  float* out = (float*)d_out;

  // workspace layout (floats): sq | pam | pD | pI | accum | ccnt | clist | XH/XL planes
  float* sq = (float*)d_ws;                               // [4096]
  int* pam = (int*)d_ws + N_;                             // [4096]
  float* pD = (float*)d_ws + 2 * N_;                      // [4096*96]
  int* pI = (int*)d_ws + 2 * N_ + N_ * 96;                // [4096*96]
  float* accum = (float*)d_ws + 2 * N_ + 2 * (N_ * 96);   // [3] (+pad to 16)
  int* ccnt = (int*)accum + 16;                           // [128]
  int* clist = ccnt + C_;                                 // [128*256]
  const size_t base_f = (size_t)(2 * N_ + 2 * (N_ * 96) + 16 + C_ + C_ * MAXC);
  const size_t split_off = ((base_f * 4 + 15) / 16) * 16;  // bytes, 16B-aligned
  unsigned short* XH = (unsigned short*)((char*)d_ws + split_off);
  unsigned short* XL = XH + (size_t)N_ * D_;
  const size_t need = split_off + (size_t)2 * N_ * D_ * 2;
  const int use_v2 = (ws_size >= need) ? 1 : 0;  // round-5 measured: ws fits (11.57MB); new need ~11.7MB

  uint32_t kp0, kp1, kq0, kq1;
  tf2x32(0u, 42u, 0u, 0u, kp0, kp1);
  tf2x32(0u, 42u, 0u, 1u, kq0, kq1);

  zero_k<<<dim3(1), dim3(128), 0, stream>>>(accum, ccnt);
  prep_k<<<dim3(N_), dim3(64), 0, stream>>>(inputs, pred, targets, sq, pam, ccnt, clist,
                                            XH, XL, use_v2, use_v2);
  if (use_v2)
    bigk3_k<<<dim3(512), dim3(256), 0, stream>>>(XH, XL, targets, sq, pD, pI);
  else
    bigk_k<<<dim3(512), dim3(256), 0, stream>>>(inputs, targets, sq, pD, pI);
  finalize_k<<<dim3(N_ / 4), dim3(256), 0, stream>>>(inputs, targets, prob, thr, sq, pam,
                                                     pD, pI, ccnt, clist, accum,
                                                     kp0, kp1, kq0, kq1, use_v2);
  writeout_k<<<dim3(1), dim3(1), 0, stream>>>(accum, out);
}

// Round 8
// 344.307 us; speedup vs baseline: 1.1732x; 1.1732x over previous
//
#include <hip/hip_runtime.h>
#include <stdint.h>
#include <math.h>

#define N_ 4096
#define D_ 512
#define C_ 128
#define MAXC 256

typedef __attribute__((ext_vector_type(8))) short bf16x8;
typedef __attribute__((ext_vector_type(4))) float f32x4;

// ---------------- Threefry-2x32-20 (JAX-compatible) ----------------
__host__ __device__ __forceinline__ uint32_t rotl32_(uint32_t x, int d) {
  return (x << d) | (x >> (32 - d));
}
__host__ __device__ inline void tf2x32(uint32_t k0, uint32_t k1,
                                       uint32_t x0, uint32_t x1,
                                       uint32_t& y0, uint32_t& y1) {
  const uint32_t k2 = k0 ^ k1 ^ 0x1BD11BDAu;
#define TF_R(rr) { x0 += x1; x1 = rotl32_(x1, rr); x1 ^= x0; }
  x0 += k0; x1 += k1;
  TF_R(13) TF_R(15) TF_R(26) TF_R(6)
  x0 += k1; x1 += k2 + 1u;
  TF_R(17) TF_R(29) TF_R(16) TF_R(24)
  x0 += k2; x1 += k0 + 2u;
  TF_R(13) TF_R(15) TF_R(26) TF_R(6)
  x0 += k0; x1 += k1 + 3u;
  TF_R(17) TF_R(29) TF_R(16) TF_R(24)
  x0 += k1; x1 += k2 + 4u;
  TF_R(13) TF_R(15) TF_R(26) TF_R(6)
  x0 += k2; x1 += k0 + 5u;
#undef TF_R
  y0 = x0; y1 = x1;
}

__device__ __forceinline__ float gumbel_ij(uint32_t k0, uint32_t k1, uint32_t m) {
  uint32_t y0, y1;
  tf2x32(k0, k1, 0u, m, y0, y1);
  uint32_t bits = y0 ^ y1;
  uint32_t vb = (bits >> 9) | 0x3f800000u;
  float f = __uint_as_float(vb) - 1.0f;
  float u = (f == 0.0f) ? 1.1754943508222875e-38f : f;
  return -logf(-logf(u));
}

// bf16 helpers (manual RNE; no NaN inputs here)
__device__ __forceinline__ unsigned short f2bf(float x) {
  unsigned int b = __float_as_uint(x);
  b += 0x7fffu + ((b >> 16) & 1u);
  return (unsigned short)(b >> 16);
}
__device__ __forceinline__ float bf2f(unsigned short u) {
  return __uint_as_float(((unsigned int)u) << 16);
}

// ---------------- Kernel Z: zero accumulators + class counters ----------------
__global__ void zero_k(float* __restrict__ accum, int* __restrict__ ccnt) {
  int t = threadIdx.x;
  if (t == 0) {
    accum[0] = 0.0f;
    ((unsigned*)accum)[1] = 0u;
    ((unsigned*)accum)[2] = 0u;
  }
  if (t < C_) ccnt[t] = 0;
}

// ---------------- Kernel A: row norms + pred argmax + frag-major bf16 split + class lists ----------------
// Frag-major layout (per plane): plane[(t*16 + kc)*512 + lane_f*8 + j]
//   t = row>>4, kc = k>>5, lane_f = (row&15) + 16*((k&31)>>3), j = k&7.
// A wave reading lane l at offset (t*16+kc)*512 + l*8 gets the exact
// mfma_f32_16x16x32_bf16 A/B fragment (row l&15, k = (l>>4)*8 + 0..7) — 1KB
// contiguous per wave load (coalescing sweet spot).
__global__ __launch_bounds__(64) void prep_k(const float* __restrict__ inputs,
                                             const float* __restrict__ pred,
                                             const int* __restrict__ targets,
                                             float* __restrict__ sq,
                                             int* __restrict__ pam,
                                             int* __restrict__ ccnt,
                                             int* __restrict__ clist,
                                             unsigned short* __restrict__ XH,
                                             unsigned short* __restrict__ XL,
                                             int do_split, int do_list) {
  int i = blockIdx.x;
  int lane = threadIdx.x;
  const float4* rp = (const float4*)(inputs + (size_t)i * D_);
  float s = 0.0f;
#pragma unroll
  for (int q = 0; q < 2; ++q) {
    float4 v = rp[lane + 64 * q];
    s += v.x * v.x + v.y * v.y + v.z * v.z + v.w * v.w;
    if (do_split) {
      unsigned short h0 = f2bf(v.x), h1 = f2bf(v.y), h2 = f2bf(v.z), h3 = f2bf(v.w);
      unsigned short g0 = f2bf(v.x - bf2f(h0)), g1 = f2bf(v.y - bf2f(h1));
      unsigned short g2 = f2bf(v.z - bf2f(h2)), g3 = f2bf(v.w - bf2f(h3));
      uint2 hp, lp;
      hp.x = (unsigned)h0 | ((unsigned)h1 << 16); hp.y = (unsigned)h2 | ((unsigned)h3 << 16);
      lp.x = (unsigned)g0 | ((unsigned)g1 << 16); lp.y = (unsigned)g2 | ((unsigned)g3 << 16);
      // k = 4*lane + 256*q + {0..3}; all 4 in one (kc, lane_f, j0..j0+3) slot.
      size_t blk = ((size_t)(i >> 4) * 16 + ((lane >> 3) + 8 * q)) * 512;
      int lf = (i & 15) + 16 * ((lane & 7) >> 1);
      int j0 = 4 * (lane & 1);
      *(uint2*)&XH[blk + lf * 8 + j0] = hp;
      *(uint2*)&XL[blk + lf * 8 + j0] = lp;
    }
  }
#pragma unroll
  for (int off = 32; off; off >>= 1) s += __shfl_down(s, off);
  if (lane == 0) sq[i] = s;

  float v0 = pred[(size_t)i * C_ + lane];
  float v1 = pred[(size_t)i * C_ + 64 + lane];
  float bv; int bi;
  if (v1 > v0) { bv = v1; bi = lane + 64; } else { bv = v0; bi = lane; }
#pragma unroll
  for (int off = 32; off; off >>= 1) {
    float ov = __shfl_down(bv, off);
    int oi = __shfl_down(bi, off);
    if (ov > bv || (ov == bv && oi < bi)) { bv = ov; bi = oi; }
  }
  if (lane == 0) {
    pam[i] = bi;
    if (do_list) {
      int t = targets[i];
      int p = atomicAdd(&ccnt[t], 1);
      if (p < MAXC) clist[t * MAXC + p] = i;
    }
  }
}

// ---------------- Kernel B v4: coalesced frag-major direct-load MFMA K-loop ----------------
// grid 512 = 64 row-blocks x 8 col-slices; block 256 = 4 waves.
// Block tile 64 rows x 512 cols; wave w owns cols [w*128, w*128+128).
__global__ __launch_bounds__(256, 2) void bigk4_k(const unsigned short* __restrict__ XH,
                                                  const unsigned short* __restrict__ XL,
                                                  const int* __restrict__ targets,
                                                  const float* __restrict__ sq,
                                                  float* __restrict__ pD,
                                                  int* __restrict__ pI) {
  __shared__ float U[8448];       // Dl[64][132]; later aliased: MD[3072] | MI[3072]
  __shared__ float sqc[512];
  __shared__ int tcs[512];
  __shared__ float sqr[64];
  __shared__ int trs[64];

  const int tid = threadIdx.x, w = tid >> 6, l = tid & 63;
  const int rb = blockIdx.x >> 3, sl = blockIdx.x & 7;
  const int rbase = rb * 64, cbase0 = sl * 512;

  sqc[tid] = sq[cbase0 + tid]; sqc[tid + 256] = sq[cbase0 + 256 + tid];
  tcs[tid] = targets[cbase0 + tid]; tcs[tid + 256] = targets[cbase0 + 256 + tid];
  if (tid < 64) { sqr[tid] = sq[rbase + tid]; trs[tid] = targets[rbase + tid]; }

  // frag-major tile base offsets (shorts): tile t block = t*16*512; +kc*512; +l*8 per lane
  const int lo = l * 8;
  size_t ta[4], tb[8];
#pragma unroll
  for (int rt = 0; rt < 4; ++rt) ta[rt] = (size_t)((rbase >> 4) + rt) * 8192;
#pragma unroll
  for (int c = 0; c < 8; ++c) tb[c] = (size_t)((cbase0 >> 4) + w * 8 + c) * 8192;

  f32x4 acc[4][8];
#pragma unroll
  for (int rt = 0; rt < 4; ++rt)
#pragma unroll
    for (int c = 0; c < 8; ++c) acc[rt][c] = (f32x4){0.f, 0.f, 0.f, 0.f};

  // Barrier-free K-loop; every load is a wave-contiguous 1KB block.
  for (int kc = 0; kc < 16; ++kc) {
    const int off = kc * 512 + lo;
    bf16x8 ah[4], al_[4];
#pragma unroll
    for (int rt = 0; rt < 4; ++rt) {
      ah[rt] = *(const bf16x8*)(XH + ta[rt] + off);
      al_[rt] = *(const bf16x8*)(XL + ta[rt] + off);
    }
#pragma unroll
    for (int c = 0; c < 8; ++c) {
      bf16x8 bh = *(const bf16x8*)(XH + tb[c] + off);
      bf16x8 bl = *(const bf16x8*)(XL + tb[c] + off);
#pragma unroll
      for (int rt = 0; rt < 4; ++rt) {
        acc[rt][c] = __builtin_amdgcn_mfma_f32_16x16x32_bf16(ah[rt], bh, acc[rt][c], 0, 0, 0);
        acc[rt][c] = __builtin_amdgcn_mfma_f32_16x16x32_bf16(ah[rt], bl, acc[rt][c], 0, 0, 0);
        acc[rt][c] = __builtin_amdgcn_mfma_f32_16x16x32_bf16(al_[rt], bh, acc[rt][c], 0, 0, 0);
      }
    }
  }

  // ---- dist + per-thread top-12 scan, 4 phases ----
  float* Dl = U;                       // [64][132]
  float dl[12]; int il[12];
#pragma unroll
  for (int q = 0; q < 12; ++q) { dl[q] = INFINITY; il[q] = 0; }
  const int srow = tid >> 2, scq = tid & 3;
  const int orow = (l >> 4) * 4;
  const int lr = l & 15;

  for (int g = 0; g < 4; ++g) {
    __syncthreads();                   // sqc/tcs visible (g=0); prev scan done (g>0)
    if (w == g) {
#pragma unroll
      for (int rt = 0; rt < 4; ++rt)
#pragma unroll
        for (int c = 0; c < 8; ++c)
#pragma unroll
          for (int r = 0; r < 4; ++r) {
            int row = rt * 16 + orow + r;
            int cl = c * 16 + lr;
            float d2 = sqr[row] + sqc[g * 128 + cl] - 2.0f * acc[rt][c][r];
            float d = (trs[row] == tcs[g * 128 + cl]) ? INFINITY : sqrtf(fmaxf(d2, 1e-12f));
            Dl[row * 132 + cl] = d;
          }
    }
    __syncthreads();
    for (int q = 0; q < 32; ++q) {
      float d = Dl[srow * 132 + scq + 4 * q];
      if (d < dl[11]) {
        int col = cbase0 + g * 128 + scq + 4 * q;
        bool placed = false;
#pragma unroll
        for (int t = 11; t >= 1; --t) {
          if (!placed) {
            if (dl[t - 1] > d) { dl[t] = dl[t - 1]; il[t] = il[t - 1]; }
            else { dl[t] = d; il[t] = col; placed = true; }
          }
        }
        if (!placed) { dl[0] = d; il[0] = col; }
      }
    }
  }

  // merge 4 per-thread lists per row -> per-(row,slice) top-12 (MD/MI alias Dl)
  __syncthreads();                     // all scans done before overwriting Dl region
  float* MD = U;                       // [256][12]
  int* MI = (int*)(U + 3072);          // [256][12]
#pragma unroll
  for (int q = 0; q < 12; ++q) { MD[tid * 12 + q] = dl[q]; MI[tid * 12 + q] = il[q]; }
  __syncthreads();
  if ((tid & 3) == 0) {
    int row = tid >> 2;
    int grow = rbase + row;
    float* outD = pD + ((size_t)grow * 8 + sl) * 12;
    int* outI = pI + ((size_t)grow * 8 + sl) * 12;
    int p0 = 0, p1 = 0, p2 = 0, p3 = 0;
    for (int o = 0; o < 12; ++o) {
      float bd = INFINITY; int bi = 0x7fffffff; int bc = 0;
      if (p0 < 12) { float d = MD[(row * 4 + 0) * 12 + p0]; int ix = MI[(row * 4 + 0) * 12 + p0]; if (d < bd || (d == bd && ix < bi)) { bd = d; bi = ix; bc = 0; } }
      if (p1 < 12) { float d = MD[(row * 4 + 1) * 12 + p1]; int ix = MI[(row * 4 + 1) * 12 + p1]; if (d < bd || (d == bd && ix < bi)) { bd = d; bi = ix; bc = 1; } }
      if (p2 < 12) { float d = MD[(row * 4 + 2) * 12 + p2]; int ix = MI[(row * 4 + 2) * 12 + p2]; if (d < bd || (d == bd && ix < bi)) { bd = d; bi = ix; bc = 2; } }
      if (p3 < 12) { float d = MD[(row * 4 + 3) * 12 + p3]; int ix = MI[(row * 4 + 3) * 12 + p3]; if (d < bd || (d == bd && ix < bi)) { bd = d; bi = ix; bc = 3; } }
      outD[o] = bd; outI[o] = bi;
      if (bc == 0) p0++; else if (bc == 1) p1++; else if (bc == 2) p2++; else p3++;
    }
  }
}

// ---------------- Kernel B v1 (fp32 fallback when ws too small) ----------------
__global__ __launch_bounds__(256, 2) void bigk_k(const float* __restrict__ inputs,
                                                 const int* __restrict__ targets,
                                                 const float* __restrict__ sq,
                                                 float* __restrict__ pD,
                                                 int* __restrict__ pI) {
  __shared__ float U[10496];
  __shared__ float sqc[256];
  __shared__ int tcs[256];
  __shared__ float sqr[64];
  __shared__ int trs[64];

  float* Al = U;
  float* Bl = U + 2176;
  float* Dl = U;
  float* MD = U;
  int* MI = (int*)(U + 3072);

  const int tid = threadIdx.x;
  const int rb = blockIdx.x >> 3, sl = blockIdx.x & 7;
  const int rbase = rb * 64, cbase0 = sl * 512;

  if (tid < 64) { sqr[tid] = sq[rbase + tid]; trs[tid] = targets[rbase + tid]; }

  float dl[12]; int il[12];
#pragma unroll
  for (int q = 0; q < 12; ++q) { dl[q] = INFINITY; il[q] = 0; }

  const int w = tid >> 6, lane = tid & 63;
  const int rg = lane >> 3, cg = lane & 7;
  const int r0 = rg * 8, c0l = w * 64 + cg * 8;
  const int srow = tid >> 2, scq = tid & 3;

  for (int ci = 0; ci < 2; ++ci) {
    const int cbase = cbase0 + ci * 256;
    __syncthreads();
    sqc[tid] = sq[cbase + tid];
    tcs[tid] = targets[cbase + tid];

    float acc[8][8];
#pragma unroll
    for (int a = 0; a < 8; ++a)
#pragma unroll
      for (int b = 0; b < 8; ++b) acc[a][b] = 0.0f;

    for (int kc = 0; kc < 16; ++kc) {
      const int kb = kc * 32;
      __syncthreads();
#pragma unroll
      for (int q = 0; q < 2; ++q) {
        int idx = tid + 256 * q;
        int row = idx >> 3, kq = idx & 7;
        float4 v = *(const float4*)(inputs + (size_t)(rbase + row) * D_ + kb + kq * 4);
        Al[(4 * kq + 0) * 68 + row] = v.x;
        Al[(4 * kq + 1) * 68 + row] = v.y;
        Al[(4 * kq + 2) * 68 + row] = v.z;
        Al[(4 * kq + 3) * 68 + row] = v.w;
      }
#pragma unroll
      for (int q = 0; q < 8; ++q) {
        int idx = tid + 256 * q;
        int col = idx >> 3, kq = idx & 7;
        float4 v = *(const float4*)(inputs + (size_t)(cbase + col) * D_ + kb + kq * 4);
        Bl[(4 * kq + 0) * 260 + col] = v.x;
        Bl[(4 * kq + 1) * 260 + col] = v.y;
        Bl[(4 * kq + 2) * 260 + col] = v.z;
        Bl[(4 * kq + 3) * 260 + col] = v.w;
      }
      __syncthreads();
#pragma unroll 4
      for (int k = 0; k < 32; ++k) {
        float4 a0 = *(const float4*)&Al[k * 68 + r0];
        float4 a1 = *(const float4*)&Al[k * 68 + r0 + 4];
        float4 b0 = *(const float4*)&Bl[k * 260 + c0l];
        float4 b1 = *(const float4*)&Bl[k * 260 + c0l + 4];
        float a_[8] = {a0.x, a0.y, a0.z, a0.w, a1.x, a1.y, a1.z, a1.w};
        float b_[8] = {b0.x, b0.y, b0.z, b0.w, b1.x, b1.y, b1.z, b1.w};
#pragma unroll
        for (int ii = 0; ii < 8; ++ii)
#pragma unroll
          for (int jj = 0; jj < 8; ++jj)
            acc[ii][jj] = fmaf(a_[ii], b_[jj], acc[ii][jj]);
      }
    }

    for (int h = 0; h < 2; ++h) {
      __syncthreads();
#pragma unroll
      for (int i = 0; i < 8; ++i) {
        float si = sqr[r0 + i];
        int ti_ = trs[r0 + i];
#pragma unroll
        for (int jj = 0; jj < 4; ++jj) {
          int j = 4 * h + jj;
          float d2 = si + sqc[c0l + j] - 2.0f * acc[i][j];
          float d = (ti_ == tcs[c0l + j]) ? INFINITY : sqrtf(fmaxf(d2, 1e-12f));
          Dl[(r0 + i) * 129 + (w * 32 + cg * 4 + jj)] = d;
        }
      }
      __syncthreads();
      for (int q = 0; q < 32; ++q) {
        float d = Dl[srow * 129 + scq * 32 + q];
        if (d < dl[11]) {
          int u = scq * 32 + q;
          int col = cbase + ((u >> 5) << 6) + (((u >> 2) & 7) << 3) + (h << 2) + (u & 3);
          bool placed = false;
#pragma unroll
          for (int t = 11; t >= 1; --t) {
            if (!placed) {
              if (dl[t - 1] > d) { dl[t] = dl[t - 1]; il[t] = il[t - 1]; }
              else { dl[t] = d; il[t] = col; placed = true; }
            }
          }
          if (!placed) { dl[0] = d; il[0] = col; }
        }
      }
    }
  }

  __syncthreads();
#pragma unroll
  for (int q = 0; q < 12; ++q) { MD[tid * 12 + q] = dl[q]; MI[tid * 12 + q] = il[q]; }
  __syncthreads();
  if ((tid & 3) == 0) {
    int row = tid >> 2;
    int grow = rbase + row;
    float* outD = pD + ((size_t)grow * 8 + sl) * 12;
    int* outI = pI + ((size_t)grow * 8 + sl) * 12;
    int p0 = 0, p1 = 0, p2 = 0, p3 = 0;
    for (int o = 0; o < 12; ++o) {
      float bd = INFINITY; int bi = 0x7fffffff; int bc = 0;
      if (p0 < 12) { float d = MD[(row * 4 + 0) * 12 + p0]; int ix = MI[(row * 4 + 0) * 12 + p0]; if (d < bd || (d == bd && ix < bi)) { bd = d; bi = ix; bc = 0; } }
      if (p1 < 12) { float d = MD[(row * 4 + 1) * 12 + p1]; int ix = MI[(row * 4 + 1) * 12 + p1]; if (d < bd || (d == bd && ix < bi)) { bd = d; bi = ix; bc = 1; } }
      if (p2 < 12) { float d = MD[(row * 4 + 2) * 12 + p2]; int ix = MI[(row * 4 + 2) * 12 + p2]; if (d < bd || (d == bd && ix < bi)) { bd = d; bi = ix; bc = 2; } }
      if (p3 < 12) { float d = MD[(row * 4 + 3) * 12 + p3]; int ix = MI[(row * 4 + 3) * 12 + p3]; if (d < bd || (d == bd && ix < bi)) { bd = d; bi = ix; bc = 3; } }
      outD[o] = bd; outI[o] = bi;
      if (bc == 0) p0++; else if (bc == 1) p1++; else if (bc == 2) p2++; else p3++;
    }
  }
}

// ---------------- Kernel C: per-row finalize (exact recompute of top-12) ----------------
__device__ __forceinline__ float wdist2(float4 xi0, float4 xi1,
                                        const float* __restrict__ inputs,
                                        const float* __restrict__ sq,
                                        int i, int j, int lane) {
  const float4* b = (const float4*)(inputs + (size_t)j * D_);
  float4 y0 = b[lane], y1 = b[lane + 64];
  float s = xi0.x * y0.x + xi0.y * y0.y + xi0.z * y0.z + xi0.w * y0.w +
            xi1.x * y1.x + xi1.y * y1.y + xi1.z * y1.z + xi1.w * y1.w;
#pragma unroll
  for (int off = 32; off; off >>= 1) s += __shfl_xor(s, off);
  float d2 = sq[i] + sq[j] - 2.0f * s;
  return sqrtf(fmaxf(d2, 1e-12f));
}

__global__ __launch_bounds__(256) void finalize_k(const float* __restrict__ inputs,
                                                  const int* __restrict__ targets,
                                                  const float* __restrict__ prob,
                                                  const float* __restrict__ thr_p,
                                                  const float* __restrict__ sq,
                                                  const int* __restrict__ pam,
                                                  const float* __restrict__ pD,
                                                  const int* __restrict__ pI,
                                                  const int* __restrict__ ccnt,
                                                  const int* __restrict__ clist,
                                                  float* __restrict__ accum,
                                                  uint32_t kp0, uint32_t kp1,
                                                  uint32_t kq0, uint32_t kq1,
                                                  int use_list) {
  const int wid = threadIdx.x >> 6, lane = threadIdx.x & 63;
  const int i = blockIdx.x * 4 + wid;
  const float thr = *thr_p;
  const int ti = targets[i];

  // gumbel argmax over same-class columns (both keys)
  float g1 = -INFINITY; int i1 = 0;
  float g2 = -INFINITY; int i2 = 0;
  int f2 = 0;
  if (use_list) {
    int cnt = ccnt[ti]; if (cnt > MAXC) cnt = MAXC;
    const int* lst = clist + (size_t)ti * MAXC;
    for (int base = 0; base < cnt; base += 64) {
      int idx = base + lane;
      if (idx < cnt) {
        int j = lst[idx];
        if (j != i) {
          uint32_t m = ((uint32_t)i << 12) | (uint32_t)j;
          float g = gumbel_ij(kp0, kp1, m);
          if (g > g1 || (g == g1 && j < i1)) { g1 = g; i1 = j; }
          if (prob[j] >= thr) {
            float gg = gumbel_ij(kq0, kq1, m);
            if (gg > g2 || (gg == g2 && j < i2)) { g2 = gg; i2 = j; }
            f2 = 1;
          }
        }
      }
    }
  } else {
    for (int j = lane; j < N_; j += 64) {
      if (targets[j] == ti && j != i) {
        uint32_t m = ((uint32_t)i << 12) | (uint32_t)j;
        float g = gumbel_ij(kp0, kp1, m);
        if (g > g1 || (g == g1 && j < i1)) { g1 = g; i1 = j; }
        if (prob[j] >= thr) {
          float gg = gumbel_ij(kq0, kq1, m);
          if (gg > g2 || (gg == g2 && j < i2)) { g2 = gg; i2 = j; }
          f2 = 1;
        }
      }
    }
  }
#pragma unroll
  for (int off = 32; off; off >>= 1) {
    float og = __shfl_xor(g1, off); int oi = __shfl_xor(i1, off);
    if (og > g1 || (og == g1 && oi < i1)) { g1 = og; i1 = oi; }
    float oh = __shfl_xor(g2, off); int oj = __shfl_xor(i2, off);
    if (oh > g2 || (oh == g2 && oj < i2)) { g2 = oh; i2 = oj; }
  }
  f2 = __any(f2);
  const int ap_idx = i1;
  const int new_pos = f2 ? i2 : ap_idx;

  const float4* arow = (const float4*)(inputs + (size_t)i * D_);
  float4 xi0 = arow[lane], xi1 = arow[lane + 64];
  const float ap0 = wdist2(xi0, xi1, inputs, sq, i, ap_idx, lane);
  const float ap_new = wdist2(xi0, xi1, inputs, sq, i, new_pos, lane);

  // merge 8 slice lists -> 12 candidate indices
  const float* rowD = pD + (size_t)i * 96;
  const int* rowI = pI + (size_t)i * 96;
  int ci_[12];
  {
    int p0 = 0, p1 = 0, p2 = 0, p3 = 0, p4 = 0, p5 = 0, p6 = 0, p7 = 0;
#pragma unroll
    for (int o = 0; o < 12; ++o) {
      float bd = INFINITY; int bi = 0x7fffffff; int bs = 0;
#define HEADQ(s, ps) if (ps < 12) { float d = rowD[(s) * 12 + ps]; int ix = rowI[(s) * 12 + ps]; if (d < bd || (d == bd && ix < bi)) { bd = d; bi = ix; bs = (s); } }
      HEADQ(0, p0) HEADQ(1, p1) HEADQ(2, p2) HEADQ(3, p3)
      HEADQ(4, p4) HEADQ(5, p5) HEADQ(6, p6) HEADQ(7, p7)
#undef HEADQ
      ci_[o] = bi;
      if (bs == 0) p0++; else if (bs == 1) p1++; else if (bs == 2) p2++; else if (bs == 3) p3++;
      else if (bs == 4) p4++; else if (bs == 5) p5++; else if (bs == 6) p6++; else p7++;
    }
  }
  // exact fp32 recompute of the 12 candidate distances
  float de[12];
#pragma unroll
  for (int o = 0; o < 12; ++o) de[o] = wdist2(xi0, xi1, inputs, sq, i, ci_[o], lane);

  // rank-0: min by (d, idx)
  float an0 = de[0]; int an_idx = ci_[0]; int minpos = 0;
#pragma unroll
  for (int o = 1; o < 12; ++o)
    if (de[o] < an0 || (de[o] == an0 && ci_[o] < an_idx)) { an0 = de[o]; an_idx = ci_[o]; minpos = o; }
  // an_B: first confident among ranks 1..11
  float anB = INFINITY; int anBi = 0x7fffffff; bool fB = false;
#pragma unroll
  for (int o = 0; o < 12; ++o) {
    if (o != minpos) {
      bool cf = prob[ci_[o]] >= thr;
      if (cf && (de[o] < anB || (de[o] == anB && ci_[o] < anBi))) { anB = de[o]; anBi = ci_[o]; fB = true; }
    }
  }
  if (!fB) {  // r = TOPK-1: the largest of the 12
    anB = de[0]; anBi = ci_[0];
#pragma unroll
    for (int o = 1; o < 12; ++o)
      if (de[o] > anB || (de[o] == anB && ci_[o] > anBi)) { anB = de[o]; anBi = ci_[o]; }
  }
  const float an_B = anB;

  if (lane == 0) {
    bool neg_conf = prob[an_idx] >= thr;
    bool pos_conf = prob[ap_idx] >= thr;
    bool is_fn = (pam[an_idx] == ti);
    bool caseB = pos_conf && !neg_conf && is_fn;
    bool swap_ = !pos_conf && (neg_conf || !is_fn);
    bool inverse = !pos_conf && !neg_conf && is_fn;
    float half = 0.5f * (ap0 + an0);
    float ap = caseB ? half : (swap_ ? ap_new : ap0);
    float an = caseB ? an_B : (swap_ ? half : an0);
    const float margin = 0.3f;
    float rl = inverse ? fmaxf(an - ap + margin, 0.0f) : fmaxf(ap - an + margin, 0.0f);
    bool conf_i = prob[i] >= thr;
    if (conf_i) {
      atomicAdd(&accum[0], rl);
      atomicAdd(((unsigned*)accum) + 2, 1u);
      if (an >= ap) atomicAdd(((unsigned*)accum) + 1, 1u);
    }
  }
}

__global__ void writeout_k(const float* __restrict__ accum, float* __restrict__ out) {
  unsigned correct = ((const unsigned*)accum)[1];
  unsigned cnt = ((const unsigned*)accum)[2];
  out[0] = accum[0] / fmaxf((float)cnt, 1.0f);
  out[1] = (float)correct;
}

extern "C" void kernel_launch(void* const* d_in, const int* in_sizes, int n_in,
                              void* d_out, int out_size, void* d_ws, size_t ws_size,
                              hipStream_t stream) {
  const float* inputs = (const float*)d_in[0];
  const float* pred = (const float*)d_in[1];
  const int* targets = (const int*)d_in[2];
  const float* prob = (const float*)d_in[4];
  const float* thr = (const float*)d_in[5];
  float* out = (float*)d_out;

  // workspace layout (floats): sq | pam | pD | pI | accum | ccnt | clist | XH/XL frag-major planes
  float* sq = (float*)d_ws;                               // [4096]
  int* pam = (int*)d_ws + N_;                             // [4096]
  float* pD = (float*)d_ws + 2 * N_;                      // [4096*96]
  int* pI = (int*)d_ws + 2 * N_ + N_ * 96;                // [4096*96]
  float* accum = (float*)d_ws + 2 * N_ + 2 * (N_ * 96);   // [3] (+pad to 16)
  int* ccnt = (int*)accum + 16;                           // [128]
  int* clist = ccnt + C_;                                 // [128*256]
  const size_t base_f = (size_t)(2 * N_ + 2 * (N_ * 96) + 16 + C_ + C_ * MAXC);
  const size_t split_off = ((base_f * 4 + 15) / 16) * 16;  // bytes, 16B-aligned
  unsigned short* XH = (unsigned short*)((char*)d_ws + split_off);
  unsigned short* XL = XH + (size_t)N_ * D_;
  const size_t need = split_off + (size_t)2 * N_ * D_ * 2;
  const int use_v2 = (ws_size >= need) ? 1 : 0;  // measured: fits (rounds 5/7 ran the MFMA path)

  uint32_t kp0, kp1, kq0, kq1;
  tf2x32(0u, 42u, 0u, 0u, kp0, kp1);
  tf2x32(0u, 42u, 0u, 1u, kq0, kq1);

  zero_k<<<dim3(1), dim3(128), 0, stream>>>(accum, ccnt);
  prep_k<<<dim3(N_), dim3(64), 0, stream>>>(inputs, pred, targets, sq, pam, ccnt, clist,
                                            XH, XL, use_v2, use_v2);
  if (use_v2)
    bigk4_k<<<dim3(512), dim3(256), 0, stream>>>(XH, XL, targets, sq, pD, pI);
  else
    bigk_k<<<dim3(512), dim3(256), 0, stream>>>(inputs, targets, sq, pD, pI);
  finalize_k<<<dim3(N_ / 4), dim3(256), 0, stream>>>(inputs, targets, prob, thr, sq, pam,
                                                     pD, pI, ccnt, clist, accum,
                                                     kp0, kp1, kq0, kq1, use_v2);
  writeout_k<<<dim3(1), dim3(1), 0, stream>>>(accum, out);
}